// Round 4
// baseline (295.030 us; speedup 1.0000x reference)
//
#include <hip/hip_runtime.h>

// out[e, i, c] = sum_j inv[e, i, j] * conv[mesh[e, j], c]
// E = 2,000,000, K = 4, C = 3.
// R1->R3: NT loads/stores cut FETCH 279->197 MB but BW pinned at ~2.7 TB/s
// => not HBM-byte-bound. Invariant limiter = 24 lane-divergent scalar gather
// dwords/thread (~1.5 GB of 64B L2 sectors). R4: one dwordx3 per vertex
// (8 gathers/thread, 3x fewer requests). Gathers cached; streams NT.

#define BLOCK 256

typedef float vfloat4 __attribute__((ext_vector_type(4)));
typedef int   vint4   __attribute__((ext_vector_type(4)));

struct F3 { float x, y, z; };   // 12 B, align 4 -> global_load_dwordx3

__global__ __launch_bounds__(BLOCK) void
elem_matmul_kernel(const float* __restrict__ conv,
                   const int* __restrict__ mesh,
                   const float* __restrict__ inv,
                   float* __restrict__ out,
                   int half, int E) {
    int t = blockIdx.x * blockDim.x + threadIdx.x;
    if (t >= half) return;

    int e0 = t;
    int e1 = t + half;
    const bool has1 = (e1 < E);

    // ---- Phase 1: index loads (both elements, independent) ----
    const vint4* mp = reinterpret_cast<const vint4*>(mesh);
    vint4 idx0 = __builtin_nontemporal_load(mp + e0);
    vint4 idx1 = has1 ? __builtin_nontemporal_load(mp + e1) : idx0;

    // ---- Phase 2: inverse-matrix stream loads (independent of idx) ----
    vfloat4 r[2][4];
    {
        const vfloat4* ip0 = reinterpret_cast<const vfloat4*>(inv) + 4 * (size_t)e0;
#pragma unroll
        for (int j = 0; j < 4; ++j) r[0][j] = __builtin_nontemporal_load(ip0 + j);
    }
    if (has1) {
        const vfloat4* ip1 = reinterpret_cast<const vfloat4*>(inv) + 4 * (size_t)e1;
#pragma unroll
        for (int j = 0; j < 4; ++j) r[1][j] = __builtin_nontemporal_load(ip1 + j);
    }

    // ---- Phase 3: gathers — ONE dwordx3 per vertex, cached (conv reuse ~20x)
    const int vs[2][4] = {{idx0.x, idx0.y, idx0.z, idx0.w},
                          {idx1.x, idx1.y, idx1.z, idx1.w}};
    F3 g[2][4];
#pragma unroll
    for (int k = 0; k < 2; ++k) {
#pragma unroll
        for (int j = 0; j < 4; ++j) {
            g[k][j] = *reinterpret_cast<const F3*>(conv + 3 * (size_t)vs[k][j]);
        }
    }

    // ---- Phase 4: compute + NT store ----
#pragma unroll
    for (int k = 0; k < 2; ++k) {
        if (k == 1 && !has1) break;
        float gc[4][3];
#pragma unroll
        for (int j = 0; j < 4; ++j) {
            gc[j][0] = g[k][j].x; gc[j][1] = g[k][j].y; gc[j][2] = g[k][j].z;
        }
        float o[4][3];
#pragma unroll
        for (int c = 0; c < 3; ++c) {
#pragma unroll
            for (int i = 0; i < 4; ++i) {
                const vfloat4 ri = r[k][i];
                o[i][c] = ri.x * gc[0][c] + ri.y * gc[1][c] +
                          ri.z * gc[2][c] + ri.w * gc[3][c];
            }
        }
        vfloat4* op = reinterpret_cast<vfloat4*>(out) + 3 * (size_t)(k == 0 ? e0 : e1);
        vfloat4 s0 = {o[0][0], o[0][1], o[0][2], o[1][0]};
        vfloat4 s1 = {o[1][1], o[1][2], o[2][0], o[2][1]};
        vfloat4 s2 = {o[2][2], o[3][0], o[3][1], o[3][2]};
        __builtin_nontemporal_store(s0, op + 0);
        __builtin_nontemporal_store(s1, op + 1);
        __builtin_nontemporal_store(s2, op + 2);
    }
}

extern "C" void kernel_launch(void* const* d_in, const int* in_sizes, int n_in,
                              void* d_out, int out_size, void* d_ws, size_t ws_size,
                              hipStream_t stream) {
    const float* conv = (const float*)d_in[0];   // (N_NODES, 3) f32
    const int* mesh = (const int*)d_in[1];       // (E, 4) i32
    const float* inv = (const float*)d_in[2];    // (E, 4, 4) f32
    float* out = (float*)d_out;                  // (E, 4, 3) f32

    const int E = in_sizes[1] / 4;
    const int half = (E + 1) / 2;
    const int grid = (half + BLOCK - 1) / BLOCK;
    elem_matmul_kernel<<<grid, BLOCK, 0, stream>>>(conv, mesh, inv, out, half, E);
}

// Round 5
// 293.323 us; speedup vs baseline: 1.0058x; 1.0058x over previous
//
#include <hip/hip_runtime.h>

// out[e, i, c] = sum_j inv[e, i, j] * conv[mesh[e, j], c]
// E = 2,000,000, K = 4, C = 3.
// R1->R4 history: NT loads+stores cut bytes 382->317 MB, BW pinned ~2.75 TB/s.
// R4 (dwordx3 gathers) exactly neutral -> compiler already merged; gathers
// not instruction-limited. R5 theory: 16 B NT stores at 48 B lane stride are
// partial-line writes -> HBM read-modify-write (WRITE_SIZE 94->112 MB when NT
// added). Fix: stage block output in LDS, store as contiguous full-line
// float4 runs (1 KB/inst), keep NT.

#define BLOCK 256

typedef float vfloat4 __attribute__((ext_vector_type(4)));
typedef int   vint4   __attribute__((ext_vector_type(4)));

struct F3 { float x, y, z; };   // 12 B -> global_load_dwordx3

__global__ __launch_bounds__(BLOCK) void
elem_matmul_kernel(const float* __restrict__ conv,
                   const int* __restrict__ mesh,
                   const float* __restrict__ inv,
                   float* __restrict__ out,
                   int half, int E) {
    __shared__ vfloat4 sbuf[3 * BLOCK];   // 12,288 B

    const int i = threadIdx.x;
    const int t = blockIdx.x * BLOCK + i;
    const bool act = (t < half);
    const int tc = act ? t : (half - 1);      // clamp: inactive lanes load
    const int e0 = tc;                        // valid addresses, results unused
    const int e1 = tc + half;                 // < E (E = 2*half)

    // ---- index loads (NT stream) ----
    const vint4* mp = reinterpret_cast<const vint4*>(mesh);
    const vint4 idx0 = __builtin_nontemporal_load(mp + e0);
    const vint4 idx1 = __builtin_nontemporal_load(mp + e1);

    // ---- inverse-matrix stream loads (NT, independent of idx) ----
    vfloat4 r[2][4];
    {
        const vfloat4* ip0 = reinterpret_cast<const vfloat4*>(inv) + 4 * (size_t)e0;
        const vfloat4* ip1 = reinterpret_cast<const vfloat4*>(inv) + 4 * (size_t)e1;
#pragma unroll
        for (int j = 0; j < 4; ++j) r[0][j] = __builtin_nontemporal_load(ip0 + j);
#pragma unroll
        for (int j = 0; j < 4; ++j) r[1][j] = __builtin_nontemporal_load(ip1 + j);
    }

    // ---- gathers (cached; conv reuse ~20x, L2/L3-resident) ----
    const int vs[2][4] = {{idx0.x, idx0.y, idx0.z, idx0.w},
                          {idx1.x, idx1.y, idx1.z, idx1.w}};
    F3 g[2][4];
#pragma unroll
    for (int k = 0; k < 2; ++k)
#pragma unroll
        for (int j = 0; j < 4; ++j)
            g[k][j] = *reinterpret_cast<const F3*>(conv + 3 * (size_t)vs[k][j]);

    // ---- compute both elements ----
    float o[2][4][3];
#pragma unroll
    for (int k = 0; k < 2; ++k) {
        float gc[4][3];
#pragma unroll
        for (int j = 0; j < 4; ++j) {
            gc[j][0] = g[k][j].x; gc[j][1] = g[k][j].y; gc[j][2] = g[k][j].z;
        }
#pragma unroll
        for (int c = 0; c < 3; ++c)
#pragma unroll
            for (int ii = 0; ii < 4; ++ii) {
                const vfloat4 ri = r[k][ii];
                o[k][ii][c] = ri.x * gc[0][c] + ri.y * gc[1][c] +
                              ri.z * gc[2][c] + ri.w * gc[3][c];
            }
    }

    // ---- stores: LDS-staged, block-contiguous full-line NT writes ----
    const int v = min(BLOCK, half - blockIdx.x * BLOCK);   // valid elems/block
    const int nvec = 3 * v;
#pragma unroll
    for (int k = 0; k < 2; ++k) {
        // thread i's element output -> LDS float4 slots 3i..3i+2
        sbuf[3 * i + 0] = (vfloat4){o[k][0][0], o[k][0][1], o[k][0][2], o[k][1][0]};
        sbuf[3 * i + 1] = (vfloat4){o[k][1][1], o[k][1][2], o[k][2][0], o[k][2][1]};
        sbuf[3 * i + 2] = (vfloat4){o[k][2][2], o[k][3][0], o[k][3][1], o[k][3][2]};
        __syncthreads();
        const size_t obase = 3 * ((size_t)blockIdx.x * BLOCK + (k ? (size_t)half : 0));
        vfloat4* op = reinterpret_cast<vfloat4*>(out) + obase;
#pragma unroll
        for (int s = i; s < 3 * BLOCK; s += BLOCK)          // s = i, i+256, i+512
            if (s < nvec)
                __builtin_nontemporal_store(sbuf[s], op + s);
        __syncthreads();
    }
}

extern "C" void kernel_launch(void* const* d_in, const int* in_sizes, int n_in,
                              void* d_out, int out_size, void* d_ws, size_t ws_size,
                              hipStream_t stream) {
    const float* conv = (const float*)d_in[0];   // (N_NODES, 3) f32
    const int* mesh = (const int*)d_in[1];       // (E, 4) i32
    const float* inv = (const float*)d_in[2];    // (E, 4, 4) f32
    float* out = (float*)d_out;                  // (E, 4, 3) f32

    const int E = in_sizes[1] / 4;
    const int half = (E + 1) / 2;
    const int grid = (half + BLOCK - 1) / BLOCK;
    elem_matmul_kernel<<<grid, BLOCK, 0, stream>>>(conv, mesh, inv, out, half, E);
}